// Round 3
// baseline (1387.589 us; speedup 1.0000x reference)
//
#include <hip/hip_runtime.h>
#include <hip/hip_bf16.h>

#define IGNORE_INDEX (-100)

using f32x4  = __attribute__((ext_vector_type(4))) float;
using bf16x8 = __attribute__((ext_vector_type(8))) short;

constexpr int BM = 256, BN = 256;
constexpr int MT = 8;      // m tiles (2048 / 256)
constexpr int NT = 500;    // n tiles (128000 / 256)
constexpr int KT64 = 32;   // k tiles of 64 (2048 / 64)
constexpr int SROWS = 2047;
constexpr int DDIM = 2048;

constexpr size_t WS_ACC_BYTES = 16384;
constexpr size_t WS_A_BYTES   = (size_t)2048 * 2048 * 2;
constexpr size_t WS_W_BYTES   = (size_t)128000 * 2048 * 2;
constexpr size_t WS_NEED      = WS_ACC_BYTES + WS_A_BYTES + WS_W_BYTES;

__device__ __forceinline__ unsigned cvt_pk_bf16(float lo, float hi) {
    unsigned r;
    asm("v_cvt_pk_bf16_f32 %0, %1, %2" : "=v"(r) : "v"(lo), "v"(hi));
    return r;
}

__device__ __forceinline__ void gload_lds16(const void* g, void* l) {
    __builtin_amdgcn_global_load_lds(
        (__attribute__((address_space(1))) void*)(g),
        (__attribute__((address_space(3))) void*)(l), 16, 0, 0);
}

// ---------------- prepass: fp32 -> bf16 (RNE) ----------------
__global__ __launch_bounds__(256)
void cvt_f32_bf16(const float* __restrict__ src, unsigned short* __restrict__ dst, size_t n8)
{
    size_t i = (size_t)blockIdx.x * 256 + threadIdx.x;
    const size_t stride = (size_t)gridDim.x * 256;
    for (; i < n8; i += stride) {
        const float4* s = (const float4*)(src + i * 8);
        float4 a = s[0], b = s[1];
        uint4 u;
        u.x = cvt_pk_bf16(a.x, a.y); u.y = cvt_pk_bf16(a.z, a.w);
        u.z = cvt_pk_bf16(b.x, b.y); u.w = cvt_pk_bf16(b.z, b.w);
        ((uint4*)dst)[i] = u;
    }
}

// ---------------- main fused GEMM + online CE epilogue (BK=64, 2-phase/tile) ----------------
__global__ __launch_bounds__(512, 2)
void ce_gemm2p(const unsigned short* __restrict__ Abf,
               const unsigned short* __restrict__ Wbf,
               const float* __restrict__ bias,
               const int* __restrict__ labels,
               float* __restrict__ sumexp,
               float* __restrict__ tgt)
{
    // 2 bufs x (A[256][64] + B[256][64]) bf16 = 128 KiB
    __shared__ __align__(16) unsigned short lds[2 * 32768];

    const int bid = blockIdx.x;
    const int L = (bid & 7) * (MT * NT / 8) + (bid >> 3);
    const int n_tile = L >> 3;
    const int m_tile = L & 7;
    const int m_base = m_tile * BM;
    const int n_base = n_tile * BN;

    const int T    = threadIdx.x;
    const int lane = T & 63;
    const int wave = T >> 6;
    const int wm = wave >> 2;   // 0..1
    const int wn = wave & 3;    // 0..3
    const int q = lane & 15;
    const int g = lane >> 4;    // 0..3
    const int rq7 = q & 7;
    // phys chunk offsets (shorts) for logical k-half 0 / 1: ch_phys = ch ^ (row&7), row&7 == q&7
    const int c0 = ((g     ) ^ rq7) << 3;
    const int c1 = ((4 + g ) ^ rq7) << 3;

    // staging: thread T fills phys slot (row = base + T>>3, chunk = T&7);
    // logical source chunk = (T&7) ^ (row&7) = (T&7) ^ ((T>>3)&7)  [involution]
    const int srow8 = T >> 3;                      // 0..63
    const int sch   = (T & 7) ^ ((T >> 3) & 7);    // 0..7

    f32x4 acc[8][4];
#pragma unroll
    for (int i = 0; i < 8; ++i)
#pragma unroll
        for (int j = 0; j < 4; ++j)
            acc[i][j] = (f32x4){0.f, 0.f, 0.f, 0.f};

    const unsigned short* Asrc = Abf + (size_t)(m_base + srow8) * DDIM + sch * 8;
    const unsigned short* Bsrc = Wbf + (size_t)(n_base + srow8) * DDIM + sch * 8;
    const int wbase = wave * 512;   // shorts: wave covers 64 lanes x 8 shorts

    auto STAGE_TILE = [&](int kt, int b) {
        const int kc = kt * 64;
#pragma unroll
        for (int i = 0; i < 4; ++i)
            gload_lds16(Asrc + (size_t)i * 64 * DDIM + kc,
                        &lds[b * 32768 + i * 4096 + wbase]);
#pragma unroll
        for (int i = 0; i < 4; ++i)
            gload_lds16(Bsrc + (size_t)i * 64 * DDIM + kc,
                        &lds[b * 32768 + 16384 + i * 4096 + wbase]);
    };

    // prologue: tile 0 -> buf 0
    STAGE_TILE(0, 0);
    asm volatile("s_waitcnt vmcnt(0)" ::: "memory");
    asm volatile("s_barrier" ::: "memory");

    for (int t = 0; t < KT64; ++t) {
        const int cur = t & 1;
        const unsigned short* As_ = &lds[cur * 32768];
        const unsigned short* Bs_ = As_ + 16384;
        const int arow = wm * 128 + q;
        const int brow = wn * 64 + q;

        // issue next tile's staging early: ~full tile of compute hides the latency
        if (t + 1 < KT64) STAGE_TILE(t + 1, cur ^ 1);

        // ---- phase 0: k-half 0, all 32 MFMA ----
        bf16x8 bfr[4], afr[8];
#pragma unroll
        for (int nf = 0; nf < 4; ++nf)
            bfr[nf] = *(const bf16x8*)&Bs_[(brow + nf * 16) * 64 + c0];
#pragma unroll
        for (int mf = 0; mf < 8; ++mf)
            afr[mf] = *(const bf16x8*)&As_[(arow + mf * 16) * 64 + c0];
        asm volatile("s_barrier" ::: "memory");
        __builtin_amdgcn_s_setprio(1);
#pragma unroll
        for (int mf = 0; mf < 8; ++mf)
#pragma unroll
            for (int nf = 0; nf < 4; ++nf)
                acc[mf][nf] = __builtin_amdgcn_mfma_f32_16x16x32_bf16(afr[mf], bfr[nf], acc[mf][nf], 0, 0, 0);
        __builtin_amdgcn_s_setprio(0);
        asm volatile("s_barrier" ::: "memory");

        // ---- phase 1: k-half 1, all 32 MFMA ----
#pragma unroll
        for (int nf = 0; nf < 4; ++nf)
            bfr[nf] = *(const bf16x8*)&Bs_[(brow + nf * 16) * 64 + c1];
#pragma unroll
        for (int mf = 0; mf < 8; ++mf)
            afr[mf] = *(const bf16x8*)&As_[(arow + mf * 16) * 64 + c1];
        asm volatile("s_barrier" ::: "memory");
        __builtin_amdgcn_s_setprio(1);
#pragma unroll
        for (int mf = 0; mf < 8; ++mf)
#pragma unroll
            for (int nf = 0; nf < 4; ++nf)
                acc[mf][nf] = __builtin_amdgcn_mfma_f32_16x16x32_bf16(afr[mf], bfr[nf], acc[mf][nf], 0, 0, 0);
        __builtin_amdgcn_s_setprio(0);
        // publish tile t+1: all 8 loads were issued ~1 tile ago -> near-free wait
        if (t + 1 < KT64) asm volatile("s_waitcnt vmcnt(0)" ::: "memory");
        asm volatile("s_barrier" ::: "memory");
    }

    // ---- epilogue: bias + exp + row-sum + target gather ----
    const int grow_base = m_base + wm * 128;
    const int gcol_base = n_base + wn * 64;
#pragma unroll
    for (int mf = 0; mf < 8; ++mf) {
        const int rb = grow_base + mf * 16 + g * 4;
        int lbl[4];
#pragma unroll
        for (int r = 0; r < 4; ++r)
            lbl[r] = (rb + r < SROWS) ? labels[rb + r + 1] : -1;
        float rsum[4] = {0.f, 0.f, 0.f, 0.f};
#pragma unroll
        for (int nf = 0; nf < 4; ++nf) {
            const int gc = gcol_base + nf * 16 + q;
            const float bz = bias[gc];
            const f32x4 v = acc[mf][nf];
#pragma unroll
            for (int r = 0; r < 4; ++r) {
                const float s = v[r] + bz;
                if (lbl[r] == gc) atomicAdd(&tgt[rb + r], s);
                rsum[r] += __expf(s);
            }
        }
#pragma unroll
        for (int r = 0; r < 4; ++r) {
#pragma unroll
            for (int off = 1; off < 16; off <<= 1)
                rsum[r] += __shfl_xor(rsum[r], off);
        }
        if (q == 0) {
#pragma unroll
            for (int r = 0; r < 4; ++r)
                if (rb + r < SROWS) atomicAdd(&sumexp[rb + r], rsum[r]);
        }
    }
}

// ---------------- fallback: fp32 in, reg-staged cvt (round-1 kernel) ----------------
__global__ __launch_bounds__(512, 2)
void ce_fused_gemm(const float* __restrict__ emb,
                   const float* __restrict__ W,
                   const float* __restrict__ bias,
                   const int* __restrict__ labels,
                   float* __restrict__ sumexp,
                   float* __restrict__ tgt)
{
    constexpr int BK = 64;
    constexpr int KT = 32;
    __shared__ __align__(16) unsigned short As[2][BM * BK];
    __shared__ __align__(16) unsigned short Bs[2][BN * BK];

    const int bid = blockIdx.x;
    const int L = (bid & 7) * (MT * NT / 8) + (bid >> 3);
    const int n_tile = L >> 3;
    const int m_tile = L & 7;
    const size_t m_base = (size_t)m_tile * BM;
    const size_t n_base = (size_t)n_tile * BN;

    const int tid  = threadIdx.x;
    const int lane = tid & 63;
    const int wave = tid >> 6;
    const int wm = wave >> 2;
    const int wn = wave & 3;
    const int q = lane & 15;
    const int g = lane >> 4;
    const int r0 = tid >> 3;
    const int kg = tid & 7;

    float4 stA[4][2], stB[4][2];
    f32x4 acc[8][4];
#pragma unroll
    for (int i = 0; i < 8; ++i)
#pragma unroll
        for (int j = 0; j < 4; ++j)
            acc[i][j] = (f32x4){0.f, 0.f, 0.f, 0.f};

    const float* Ab = emb + m_base * DDIM + (size_t)kg * 8;
    const float* Bb = W   + n_base * DDIM + (size_t)kg * 8;

#define STAGE_LOAD(kt_) { \
    const size_t ko = (size_t)(kt_) * BK; \
    _Pragma("unroll") \
    for (int p = 0; p < 4; ++p) { \
        const int row = r0 + p * 64; \
        const float4* pa = (const float4*)(Ab + (size_t)row * DDIM + ko); \
        stA[p][0] = pa[0]; stA[p][1] = pa[1]; \
        const float4* pb = (const float4*)(Bb + (size_t)row * DDIM + ko); \
        stB[p][0] = pb[0]; stB[p][1] = pb[1]; \
    } }

#define STAGE_WRITE(bf_) { \
    _Pragma("unroll") \
    for (int p = 0; p < 4; ++p) { \
        const int row = r0 + p * 64; \
        const int sw = (kg * 8) ^ ((row & 7) << 3); \
        uint4 ua; \
        ua.x = cvt_pk_bf16(stA[p][0].x, stA[p][0].y); \
        ua.y = cvt_pk_bf16(stA[p][0].z, stA[p][0].w); \
        ua.z = cvt_pk_bf16(stA[p][1].x, stA[p][1].y); \
        ua.w = cvt_pk_bf16(stA[p][1].z, stA[p][1].w); \
        *(uint4*)&As[bf_][row * BK + sw] = ua; \
        uint4 ub; \
        ub.x = cvt_pk_bf16(stB[p][0].x, stB[p][0].y); \
        ub.y = cvt_pk_bf16(stB[p][0].z, stB[p][0].w); \
        ub.z = cvt_pk_bf16(stB[p][1].x, stB[p][1].y); \
        ub.w = cvt_pk_bf16(stB[p][1].z, stB[p][1].w); \
        *(uint4*)&Bs[bf_][row * BK + sw] = ub; \
    } }

#define COMPUTE(bf_) { \
    _Pragma("unroll") \
    for (int kh = 0; kh < 2; ++kh) { \
        const int c = kh * 32 + g * 8; \
        bf16x8 bfr[4]; \
        _Pragma("unroll") \
        for (int nf = 0; nf < 4; ++nf) { \
            const int rr = wn * 64 + nf * 16 + q; \
            bfr[nf] = *(const bf16x8*)&Bs[bf_][rr * BK + (c ^ ((rr & 7) << 3))]; \
        } \
        _Pragma("unroll") \
        for (int mf = 0; mf < 8; ++mf) { \
            const int rr = wm * 128 + mf * 16 + q; \
            bf16x8 afr = *(const bf16x8*)&As[bf_][rr * BK + (c ^ ((rr & 7) << 3))]; \
            _Pragma("unroll") \
            for (int nf = 0; nf < 4; ++nf) \
                acc[mf][nf] = __builtin_amdgcn_mfma_f32_16x16x32_bf16(afr, bfr[nf], acc[mf][nf], 0, 0, 0); \
        } \
    } }

    STAGE_LOAD(0);
    STAGE_WRITE(0);
    __syncthreads();

    int buf = 0;
    for (int kt = 0; kt < KT; ++kt) {
        if (kt + 1 < KT) STAGE_LOAD(kt + 1);
        COMPUTE(buf);
        if (kt + 1 < KT) STAGE_WRITE(buf ^ 1);
        __syncthreads();
        buf ^= 1;
    }

    const int grow_base = (int)m_base + wm * 128;
    const int gcol_base = (int)n_base + wn * 64;
#pragma unroll
    for (int mf = 0; mf < 8; ++mf) {
        const int rb = grow_base + mf * 16 + g * 4;
        int lbl[4];
#pragma unroll
        for (int r = 0; r < 4; ++r)
            lbl[r] = (rb + r < SROWS) ? labels[rb + r + 1] : -1;
        float rsum[4] = {0.f, 0.f, 0.f, 0.f};
#pragma unroll
        for (int nf = 0; nf < 4; ++nf) {
            const int gc = gcol_base + nf * 16 + q;
            const float bz = bias[gc];
            const f32x4 v = acc[mf][nf];
#pragma unroll
            for (int r = 0; r < 4; ++r) {
                const float s = v[r] + bz;
                if (lbl[r] == gc) atomicAdd(&tgt[rb + r], s);
                rsum[r] += __expf(s);
            }
        }
#pragma unroll
        for (int r = 0; r < 4; ++r) {
#pragma unroll
            for (int off = 1; off < 16; off <<= 1)
                rsum[r] += __shfl_xor(rsum[r], off);
        }
        if (q == 0) {
#pragma unroll
            for (int r = 0; r < 4; ++r)
                if (rb + r < SROWS) atomicAdd(&sumexp[rb + r], rsum[r]);
        }
    }
#undef STAGE_LOAD
#undef STAGE_WRITE
#undef COMPUTE
}

__global__ void ce_finalize(const float* __restrict__ sumexp,
                            const float* __restrict__ tgt,
                            const int* __restrict__ labels,
                            float* __restrict__ out)
{
    const int tid = threadIdx.x;
    float acc = 0.f, cnt = 0.f;
    for (int s = tid; s < SROWS; s += 256) {
        if (labels[s + 1] != IGNORE_INDEX) {
            acc += __logf(sumexp[s]) - tgt[s];
            cnt += 1.f;
        }
    }
#pragma unroll
    for (int off = 32; off > 0; off >>= 1) {
        acc += __shfl_down(acc, off);
        cnt += __shfl_down(cnt, off);
    }
    __shared__ float sa[4], sc[4];
    if ((tid & 63) == 0) { sa[tid >> 6] = acc; sc[tid >> 6] = cnt; }
    __syncthreads();
    if (tid == 0) {
        float a = sa[0] + sa[1] + sa[2] + sa[3];
        float c = sc[0] + sc[1] + sc[2] + sc[3];
        out[0] = a / fmaxf(c, 1.f);
    }
}

extern "C" void kernel_launch(void* const* d_in, const int* in_sizes, int n_in,
                              void* d_out, int out_size, void* d_ws, size_t ws_size,
                              hipStream_t stream)
{
    const float* emb    = (const float*)d_in[1];
    const float* W      = (const float*)d_in[2];
    const float* bias   = (const float*)d_in[3];
    const int*   labels = (const int*)d_in[4];

    float* wsf    = (float*)d_ws;
    float* sumexp = wsf;
    float* tgt    = wsf + 2048;

    hipMemsetAsync(d_ws, 0, WS_ACC_BYTES, stream);

    if (ws_size >= WS_NEED) {
        unsigned short* Abf = (unsigned short*)((char*)d_ws + WS_ACC_BYTES);
        unsigned short* Wbf = (unsigned short*)((char*)d_ws + WS_ACC_BYTES + WS_A_BYTES);
        cvt_f32_bf16<<<dim3(2048), dim3(256), 0, stream>>>(W, Wbf, (size_t)128000 * 2048 / 8);
        cvt_f32_bf16<<<dim3(256),  dim3(256), 0, stream>>>(emb, Abf, (size_t)2048 * 2048 / 8);
        ce_gemm2p<<<dim3(MT * NT), dim3(512), 0, stream>>>(Abf, Wbf, bias, labels, sumexp, tgt);
    } else {
        ce_fused_gemm<<<dim3(MT * NT), dim3(512), 0, stream>>>(emb, W, bias, labels, sumexp, tgt);
    }
    ce_finalize<<<dim3(1), dim3(256), 0, stream>>>(sumexp, tgt, labels, (float*)d_out);
}

// Round 4
// 1249.082 us; speedup vs baseline: 1.1109x; 1.1109x over previous
//
#include <hip/hip_runtime.h>
#include <hip/hip_bf16.h>

#define IGNORE_INDEX (-100)

using f32x4  = __attribute__((ext_vector_type(4))) float;
using bf16x8 = __attribute__((ext_vector_type(8))) short;

constexpr int BM = 256, BN = 256;
constexpr int MT = 8;      // m tiles (2048 / 256)
constexpr int NT = 500;    // n tiles (128000 / 256)
constexpr int KT64 = 32;   // k tiles of 64 (2048 / 64)
constexpr int SROWS = 2047;
constexpr int DDIM = 2048;

constexpr size_t WS_ACC_BYTES = 16384;
constexpr size_t WS_A_BYTES   = (size_t)2048 * 2048 * 2;
constexpr size_t WS_W_BYTES   = (size_t)128000 * 2048 * 2;
constexpr size_t WS_NEED      = WS_ACC_BYTES + WS_A_BYTES + WS_W_BYTES;

__device__ __forceinline__ unsigned cvt_pk_bf16(float lo, float hi) {
    unsigned r;
    asm("v_cvt_pk_bf16_f32 %0, %1, %2" : "=v"(r) : "v"(lo), "v"(hi));
    return r;
}

__device__ __forceinline__ void gload_lds16(const void* g, void* l) {
    __builtin_amdgcn_global_load_lds(
        (__attribute__((address_space(1))) void*)(g),
        (__attribute__((address_space(3))) void*)(l), 16, 0, 0);
}

// ---------------- prepass: fp32 -> bf16 (RNE) ----------------
__global__ __launch_bounds__(256)
void cvt_f32_bf16(const float* __restrict__ src, unsigned short* __restrict__ dst, size_t n8)
{
    size_t i = (size_t)blockIdx.x * 256 + threadIdx.x;
    const size_t stride = (size_t)gridDim.x * 256;
    for (; i < n8; i += stride) {
        const float4* s = (const float4*)(src + i * 8);
        float4 a = s[0], b = s[1];
        uint4 u;
        u.x = cvt_pk_bf16(a.x, a.y); u.y = cvt_pk_bf16(a.z, a.w);
        u.z = cvt_pk_bf16(b.x, b.y); u.w = cvt_pk_bf16(b.z, b.w);
        ((uint4*)dst)[i] = u;
    }
}

// ---------------- main fused GEMM + CE epilogue: m201-style 8-phase schedule ----------------
__global__ __launch_bounds__(512, 2)
void ce_gemm8p(const unsigned short* __restrict__ Abf,
               const unsigned short* __restrict__ Wbf,
               const float* __restrict__ bias,
               const int* __restrict__ labels,
               float* __restrict__ sumexp,
               float* __restrict__ tgt)
{
    // 2 bufs x (A[256][64] + B[256][64]) bf16 = 128 KiB
    __shared__ __align__(16) unsigned short lds[2 * 32768];

    const int bid = blockIdx.x;
    const int L = (bid & 7) * (MT * NT / 8) + (bid >> 3);
    const int n_tile = L >> 3;
    const int m_tile = L & 7;
    const int m_base = m_tile * BM;
    const int n_base = n_tile * BN;

    const int T    = threadIdx.x;
    const int lane = T & 63;
    const int wave = T >> 6;
    const int wm = wave >> 2;   // 0..1
    const int wn = wave & 3;    // 0..3
    const int q = lane & 15;
    const int g = lane >> 4;    // 0..3
    const int rq7 = q & 7;
    // phys chunk offsets (shorts) for logical k-half 0 / 1 (chunk-XOR swizzle, involution)
    const int c0 = ((g    ) ^ rq7) << 3;
    const int c1 = ((4 + g) ^ rq7) << 3;

    // staging: thread T fills phys slot (row = base + T>>3, chunk = T&7);
    // logical source chunk = (T&7) ^ ((T>>3)&7)
    const int srow8 = T >> 3;
    const int sch   = (T & 7) ^ ((T >> 3) & 7);

    f32x4 acc[8][4];
#pragma unroll
    for (int i = 0; i < 8; ++i)
#pragma unroll
        for (int j = 0; j < 4; ++j)
            acc[i][j] = (f32x4){0.f, 0.f, 0.f, 0.f};

    const unsigned short* Asrc = Abf + (size_t)(m_base + srow8) * DDIM + sch * 8;
    const unsigned short* Bsrc = Wbf + (size_t)(n_base + srow8) * DDIM + sch * 8;
    const int wbase = wave * 512;   // shorts

    // one half-tile = 2 gload_lds per wave (128 rows x 64 cols bf16)
    auto STAGE_A = [&](int kt, int h) {
        const int kc = kt * 64; const int b = (kt & 1) * 32768;
#pragma unroll
        for (int i = 0; i < 2; ++i) {
            const int blk = 2 * h + i;
            gload_lds16(Asrc + (size_t)blk * 64 * DDIM + kc, &lds[b + blk * 4096 + wbase]);
        }
    };
    auto STAGE_B = [&](int kt, int h) {
        const int kc = kt * 64; const int b = (kt & 1) * 32768;
#pragma unroll
        for (int i = 0; i < 2; ++i) {
            const int blk = 2 * h + i;
            gload_lds16(Bsrc + (size_t)blk * 64 * DDIM + kc, &lds[b + 16384 + blk * 4096 + wbase]);
        }
    };

    const int arow = wm * 128 + q;
    const int brow = wn * 64 + q;
    bf16x8 bfr[8];   // B frags of current K-tile (set at phase j==0, live 4 phases)

    // PH: one phase. j = quadrant (mf pair 2j,2j+1), BB = lds byte-base of tile buffer (shorts idx)
#define PH(j, BB, STAGE_STMT, WAIT_STMT) { \
    const unsigned short* As_ = &lds[BB]; \
    const unsigned short* Bs_ = &lds[(BB) + 16384]; \
    bf16x8 aA0 = *(const bf16x8*)&As_[(arow + (2*(j)    ) * 16) * 64 + c0]; \
    bf16x8 aB0 = *(const bf16x8*)&As_[(arow + (2*(j)    ) * 16) * 64 + c1]; \
    bf16x8 aA1 = *(const bf16x8*)&As_[(arow + (2*(j) + 1) * 16) * 64 + c0]; \
    bf16x8 aB1 = *(const bf16x8*)&As_[(arow + (2*(j) + 1) * 16) * 64 + c1]; \
    if ((j) == 0) { \
        _Pragma("unroll") \
        for (int nf = 0; nf < 4; ++nf) { \
            bfr[nf]     = *(const bf16x8*)&Bs_[(brow + nf * 16) * 64 + c0]; \
            bfr[4 + nf] = *(const bf16x8*)&Bs_[(brow + nf * 16) * 64 + c1]; \
        } \
    } \
    STAGE_STMT; \
    if ((j) == 0) asm volatile("s_waitcnt lgkmcnt(8)" ::: "memory"); \
    asm volatile("s_barrier" ::: "memory"); \
    asm volatile("s_waitcnt lgkmcnt(0)" ::: "memory"); \
    __builtin_amdgcn_s_setprio(1); \
    _Pragma("unroll") \
    for (int nf = 0; nf < 4; ++nf) \
        acc[2*(j)][nf] = __builtin_amdgcn_mfma_f32_16x16x32_bf16(aA0, bfr[nf], acc[2*(j)][nf], 0, 0, 0); \
    _Pragma("unroll") \
    for (int nf = 0; nf < 4; ++nf) \
        acc[2*(j)][nf] = __builtin_amdgcn_mfma_f32_16x16x32_bf16(aB0, bfr[4+nf], acc[2*(j)][nf], 0, 0, 0); \
    _Pragma("unroll") \
    for (int nf = 0; nf < 4; ++nf) \
        acc[2*(j)+1][nf] = __builtin_amdgcn_mfma_f32_16x16x32_bf16(aA1, bfr[nf], acc[2*(j)+1][nf], 0, 0, 0); \
    _Pragma("unroll") \
    for (int nf = 0; nf < 4; ++nf) \
        acc[2*(j)+1][nf] = __builtin_amdgcn_mfma_f32_16x16x32_bf16(aB1, bfr[4+nf], acc[2*(j)+1][nf], 0, 0, 0); \
    __builtin_amdgcn_s_setprio(0); \
    WAIT_STMT; \
    asm volatile("s_barrier" ::: "memory"); \
}

    // ---- prologue: tile 0 (buf0) fully + B halves of tile 1 (buf1) ----
    STAGE_A(0, 0); STAGE_A(0, 1); STAGE_B(0, 0); STAGE_B(0, 1);   // 8 loads
    STAGE_B(1, 0); STAGE_B(1, 1);                                 // 4 loads
    asm volatile("s_waitcnt vmcnt(4)" ::: "memory");               // tile 0 landed
    asm volatile("s_barrier" ::: "memory");

    // ---- main loop: 16 iterations x 2 K-tiles ----
    for (int i = 0; i < 16; ++i) {
        const int t0 = 2 * i, t1 = 2 * i + 1;
        const bool st = (i < 15);
        // tile t0 in buf0 (base 0)
        PH(0, 0, { STAGE_A(t1, 0); }, {});
        PH(1, 0, { STAGE_A(t1, 1); }, {});
        PH(2, 0, { if (st) STAGE_B(t0 + 2, 0); }, {});
        PH(3, 0, { if (st) STAGE_B(t0 + 2, 1); },
                 { if (st) { asm volatile("s_waitcnt vmcnt(4)" ::: "memory"); }
                   else    { asm volatile("s_waitcnt vmcnt(0)" ::: "memory"); } });
        // tile t1 in buf1 (base 32768)
        PH(0, 32768, { if (st) STAGE_A(t0 + 2, 0); }, {});
        PH(1, 32768, { if (st) STAGE_A(t0 + 2, 1); }, {});
        PH(2, 32768, { if (st) STAGE_B(t1 + 2, 0); }, {});
        PH(3, 32768, { if (st) STAGE_B(t1 + 2, 1); },
                     { if (st) { asm volatile("s_waitcnt vmcnt(4)" ::: "memory"); } });
    }
#undef PH

    // ---- epilogue: bias + exp + row-sum + target gather ----
    const int grow_base = m_base + wm * 128;
    const int gcol_base = n_base + wn * 64;
#pragma unroll
    for (int mf = 0; mf < 8; ++mf) {
        const int rb = grow_base + mf * 16 + g * 4;
        int lbl[4];
#pragma unroll
        for (int r = 0; r < 4; ++r)
            lbl[r] = (rb + r < SROWS) ? labels[rb + r + 1] : -1;
        float rsum[4] = {0.f, 0.f, 0.f, 0.f};
#pragma unroll
        for (int nf = 0; nf < 4; ++nf) {
            const int gc = gcol_base + nf * 16 + q;
            const float bz = bias[gc];
            const f32x4 v = acc[mf][nf];
#pragma unroll
            for (int r = 0; r < 4; ++r) {
                const float s = v[r] + bz;
                if (lbl[r] == gc) atomicAdd(&tgt[rb + r], s);
                rsum[r] += __expf(s);
            }
        }
#pragma unroll
        for (int r = 0; r < 4; ++r) {
#pragma unroll
            for (int off = 1; off < 16; off <<= 1)
                rsum[r] += __shfl_xor(rsum[r], off);
        }
        if (q == 0) {
#pragma unroll
            for (int r = 0; r < 4; ++r)
                if (rb + r < SROWS) atomicAdd(&sumexp[rb + r], rsum[r]);
        }
    }
}

// ---------------- fallback: fp32 in, reg-staged cvt (round-1 kernel) ----------------
__global__ __launch_bounds__(512, 2)
void ce_fused_gemm(const float* __restrict__ emb,
                   const float* __restrict__ W,
                   const float* __restrict__ bias,
                   const int* __restrict__ labels,
                   float* __restrict__ sumexp,
                   float* __restrict__ tgt)
{
    constexpr int BK = 64;
    constexpr int KT = 32;
    __shared__ __align__(16) unsigned short As[2][BM * BK];
    __shared__ __align__(16) unsigned short Bs[2][BN * BK];

    const int bid = blockIdx.x;
    const int L = (bid & 7) * (MT * NT / 8) + (bid >> 3);
    const int n_tile = L >> 3;
    const int m_tile = L & 7;
    const size_t m_base = (size_t)m_tile * BM;
    const size_t n_base = (size_t)n_tile * BN;

    const int tid  = threadIdx.x;
    const int lane = tid & 63;
    const int wave = tid >> 6;
    const int wm = wave >> 2;
    const int wn = wave & 3;
    const int q = lane & 15;
    const int g = lane >> 4;
    const int r0 = tid >> 3;
    const int kg = tid & 7;

    float4 stA[4][2], stB[4][2];
    f32x4 acc[8][4];
#pragma unroll
    for (int i = 0; i < 8; ++i)
#pragma unroll
        for (int j = 0; j < 4; ++j)
            acc[i][j] = (f32x4){0.f, 0.f, 0.f, 0.f};

    const float* Ab = emb + m_base * DDIM + (size_t)kg * 8;
    const float* Bb = W   + n_base * DDIM + (size_t)kg * 8;

#define STAGE_LOAD(kt_) { \
    const size_t ko = (size_t)(kt_) * BK; \
    _Pragma("unroll") \
    for (int p = 0; p < 4; ++p) { \
        const int row = r0 + p * 64; \
        const float4* pa = (const float4*)(Ab + (size_t)row * DDIM + ko); \
        stA[p][0] = pa[0]; stA[p][1] = pa[1]; \
        const float4* pb = (const float4*)(Bb + (size_t)row * DDIM + ko); \
        stB[p][0] = pb[0]; stB[p][1] = pb[1]; \
    } }

#define STAGE_WRITE(bf_) { \
    _Pragma("unroll") \
    for (int p = 0; p < 4; ++p) { \
        const int row = r0 + p * 64; \
        const int sw = (kg * 8) ^ ((row & 7) << 3); \
        uint4 ua; \
        ua.x = cvt_pk_bf16(stA[p][0].x, stA[p][0].y); \
        ua.y = cvt_pk_bf16(stA[p][0].z, stA[p][0].w); \
        ua.z = cvt_pk_bf16(stA[p][1].x, stA[p][1].y); \
        ua.w = cvt_pk_bf16(stA[p][1].z, stA[p][1].w); \
        *(uint4*)&As[bf_][row * BK + sw] = ua; \
        uint4 ub; \
        ub.x = cvt_pk_bf16(stB[p][0].x, stB[p][0].y); \
        ub.y = cvt_pk_bf16(stB[p][0].z, stB[p][0].w); \
        ub.z = cvt_pk_bf16(stB[p][1].x, stB[p][1].y); \
        ub.w = cvt_pk_bf16(stB[p][1].z, stB[p][1].w); \
        *(uint4*)&Bs[bf_][row * BK + sw] = ub; \
    } }

#define COMPUTE(bf_) { \
    _Pragma("unroll") \
    for (int kh = 0; kh < 2; ++kh) { \
        const int c = kh * 32 + g * 8; \
        bf16x8 bfr[4]; \
        _Pragma("unroll") \
        for (int nf = 0; nf < 4; ++nf) { \
            const int rr = wn * 64 + nf * 16 + q; \
            bfr[nf] = *(const bf16x8*)&Bs[bf_][rr * BK + (c ^ ((rr & 7) << 3))]; \
        } \
        _Pragma("unroll") \
        for (int mf = 0; mf < 8; ++mf) { \
            const int rr = wm * 128 + mf * 16 + q; \
            bf16x8 afr = *(const bf16x8*)&As[bf_][rr * BK + (c ^ ((rr & 7) << 3))]; \
            _Pragma("unroll") \
            for (int nf = 0; nf < 4; ++nf) \
                acc[mf][nf] = __builtin_amdgcn_mfma_f32_16x16x32_bf16(afr, bfr[nf], acc[mf][nf], 0, 0, 0); \
        } \
    } }

    STAGE_LOAD(0);
    STAGE_WRITE(0);
    __syncthreads();

    int buf = 0;
    for (int kt = 0; kt < KT; ++kt) {
        if (kt + 1 < KT) STAGE_LOAD(kt + 1);
        COMPUTE(buf);
        if (kt + 1 < KT) STAGE_WRITE(buf ^ 1);
        __syncthreads();
        buf ^= 1;
    }

    const int grow_base = (int)m_base + wm * 128;
    const int gcol_base = (int)n_base + wn * 64;
#pragma unroll
    for (int mf = 0; mf < 8; ++mf) {
        const int rb = grow_base + mf * 16 + g * 4;
        int lbl[4];
#pragma unroll
        for (int r = 0; r < 4; ++r)
            lbl[r] = (rb + r < SROWS) ? labels[rb + r + 1] : -1;
        float rsum[4] = {0.f, 0.f, 0.f, 0.f};
#pragma unroll
        for (int nf = 0; nf < 4; ++nf) {
            const int gc = gcol_base + nf * 16 + q;
            const float bz = bias[gc];
            const f32x4 v = acc[mf][nf];
#pragma unroll
            for (int r = 0; r < 4; ++r) {
                const float s = v[r] + bz;
                if (lbl[r] == gc) atomicAdd(&tgt[rb + r], s);
                rsum[r] += __expf(s);
            }
        }
#pragma unroll
        for (int r = 0; r < 4; ++r) {
#pragma unroll
            for (int off = 1; off < 16; off <<= 1)
                rsum[r] += __shfl_xor(rsum[r], off);
        }
        if (q == 0) {
#pragma unroll
            for (int r = 0; r < 4; ++r)
                if (rb + r < SROWS) atomicAdd(&sumexp[rb + r], rsum[r]);
        }
    }
#undef STAGE_LOAD
#undef STAGE_WRITE
#undef COMPUTE
}

__global__ void ce_finalize(const float* __restrict__ sumexp,
                            const float* __restrict__ tgt,
                            const int* __restrict__ labels,
                            float* __restrict__ out)
{
    const int tid = threadIdx.x;
    float acc = 0.f, cnt = 0.f;
    for (int s = tid; s < SROWS; s += 256) {
        if (labels[s + 1] != IGNORE_INDEX) {
            acc += __logf(sumexp[s]) - tgt[s];
            cnt += 1.f;
        }
    }
#pragma unroll
    for (int off = 32; off > 0; off >>= 1) {
        acc += __shfl_down(acc, off);
        cnt += __shfl_down(cnt, off);
    }
    __shared__ float sa[4], sc[4];
    if ((tid & 63) == 0) { sa[tid >> 6] = acc; sc[tid >> 6] = cnt; }
    __syncthreads();
    if (tid == 0) {
        float a = sa[0] + sa[1] + sa[2] + sa[3];
        float c = sc[0] + sc[1] + sc[2] + sc[3];
        out[0] = a / fmaxf(c, 1.f);
    }
}

extern "C" void kernel_launch(void* const* d_in, const int* in_sizes, int n_in,
                              void* d_out, int out_size, void* d_ws, size_t ws_size,
                              hipStream_t stream)
{
    const float* emb    = (const float*)d_in[1];
    const float* W      = (const float*)d_in[2];
    const float* bias   = (const float*)d_in[3];
    const int*   labels = (const int*)d_in[4];

    float* wsf    = (float*)d_ws;
    float* sumexp = wsf;
    float* tgt    = wsf + 2048;

    hipMemsetAsync(d_ws, 0, WS_ACC_BYTES, stream);

    if (ws_size >= WS_NEED) {
        unsigned short* Abf = (unsigned short*)((char*)d_ws + WS_ACC_BYTES);
        unsigned short* Wbf = (unsigned short*)((char*)d_ws + WS_ACC_BYTES + WS_A_BYTES);
        cvt_f32_bf16<<<dim3(2048), dim3(256), 0, stream>>>(W, Wbf, (size_t)128000 * 2048 / 8);
        cvt_f32_bf16<<<dim3(256),  dim3(256), 0, stream>>>(emb, Abf, (size_t)2048 * 2048 / 8);
        ce_gemm8p<<<dim3(MT * NT), dim3(512), 0, stream>>>(Abf, Wbf, bias, labels, sumexp, tgt);
    } else {
        ce_fused_gemm<<<dim3(MT * NT), dim3(512), 0, stream>>>(emb, W, bias, labels, sumexp, tgt);
    }
    ce_finalize<<<dim3(1), dim3(256), 0, stream>>>(sumexp, tgt, labels, (float*)d_out);
}